// Round 8
// baseline (108.375 us; speedup 1.0000x reference)
//
#include <hip/hip_runtime.h>
#include <math.h>

#define M_ROWS 8192   // B*S
#define KDIM   8192   // V
#define NDIM   512    // D
#define RCAP   512    // list slots per row (mean nnz 82, sigma 9)
#define RPB    16     // rows per block -> 512 blocks, 5 epochs of 4 rows

typedef float    f32x4  __attribute__((ext_vector_type(4)));
typedef unsigned u32x4  __attribute__((ext_vector_type(4)));
typedef __bf16   bf16x8 __attribute__((ext_vector_type(8)));

// ---------------------------------------------------------------------------
// K1: W [512, 8192] f32 -> WT [8192, 512] bf16 (d_ws, 8 MB).
__global__ __launch_bounds__(256)
void transpose_w(const float* __restrict__ W, __bf16* __restrict__ WT) {
  __shared__ float tile[64][65];
  const int t  = threadIdx.x;
  const int v0 = (blockIdx.x & 127) << 6;
  const int d0 = (blockIdx.x >> 7) << 6;
  #pragma unroll
  for (int i = 0; i < 4; ++i) {
    int idx = i * 256 + t;
    int r = idx >> 4;
    int c = (idx & 15) << 2;
    f32x4 val = *(const f32x4*)(W + (size_t)(d0 + r) * KDIM + v0 + c);
    tile[r][c + 0] = val.x; tile[r][c + 1] = val.y;
    tile[r][c + 2] = val.z; tile[r][c + 3] = val.w;
  }
  __syncthreads();
  #pragma unroll
  for (int i = 0; i < 2; ++i) {
    int idx = i * 256 + t;
    int vr = idx >> 3;
    int d8 = (idx & 7) << 3;
    bf16x8 u;
    #pragma unroll
    for (int j = 0; j < 8; ++j) u[j] = (__bf16)tile[d8 + j][vr];
    *(bf16x8*)(WT + (size_t)(v0 + vr) * NDIM + d0 + d8) = u;
  }
}

// ---------------------------------------------------------------------------
// K2: producer-consumer pipelined SpMM + tanh.
// 8 waves/block: waves 0-3 SCAN (stream A rows, ballot-compact (bf16|v)
// pairs into double-buffered LDS lists); waves 4-7 GATHER the previous
// epoch's lists (WT row gathers from L2/L3 + FMA + tanh + store).
// The HBM scan stream and the cache gather stream run CONCURRENTLY on
// different waves -> phase times max() instead of sum().
// Exact for any density: ballot enumerates actual nonzeros; overflow
// (never at ~1%) signals a sentinel count -> gatherer does exact re-scan.
__global__ __launch_bounds__(512, 4)
void spmm_pipe(const float* __restrict__ A, const __bf16* __restrict__ WT,
               float* __restrict__ C) {
  __shared__ unsigned lists[2][4][RCAP];   // 16 KB, double-buffered
  __shared__ unsigned counts[2][4];
  const int lane = threadIdx.x & 63;
  const int w    = threadIdx.x >> 6;
  const int row0 = blockIdx.x * RPB;
  const char* wtb = (const char*)WT;

#define FMA8(f, q)                                                          \
  {                                                                         \
    a0 = fmaf(f, __uint_as_float((q).x << 16), a0);                         \
    a1 = fmaf(f, __uint_as_float((q).x & 0xffff0000u), a1);                 \
    a2 = fmaf(f, __uint_as_float((q).y << 16), a2);                         \
    a3 = fmaf(f, __uint_as_float((q).y & 0xffff0000u), a3);                 \
    a4 = fmaf(f, __uint_as_float((q).z << 16), a4);                         \
    a5 = fmaf(f, __uint_as_float((q).z & 0xffff0000u), a5);                 \
    a6 = fmaf(f, __uint_as_float((q).w << 16), a6);                         \
    a7 = fmaf(f, __uint_as_float((q).w & 0xffff0000u), a7);                 \
  }

  for (int e = 0; e < 5; ++e) {
    if (w < 4) {
      // ---------------- SCAN role: row row0 + e*4 + w -> lists[e&1][w]
      if (e < 4) {
        const float* arow = A + (size_t)(row0 + e * 4 + w) * KDIM;
        unsigned* rl = &lists[e & 1][w][0];
        const unsigned long long ltmask = (1ull << lane) - 1ull;
        unsigned cur = 0;
        bool ovf = false;
        f32x4 bufs[4];
        #pragma unroll
        for (int p = 0; p < 4; ++p)
          bufs[p] = __builtin_nontemporal_load(
              (const f32x4*)(arow + p * 256 + lane * 4));
        #pragma unroll 4
        for (int pos = 0; pos < 32; ++pos) {
          f32x4 av = bufs[pos & 3];
          if (pos + 4 < 32)
            bufs[pos & 3] = __builtin_nontemporal_load(
                (const f32x4*)(arow + (pos + 4) * 256 + lane * 4));
          #pragma unroll
          for (int j = 0; j < 4; ++j) {
            unsigned long long msk = __ballot(av[j] != 0.0f);
            if (msk == 0) continue;
            unsigned cnt = (unsigned)__popcll(msk);
            if (cur + cnt <= RCAP) {
              if (av[j] != 0.0f) {
                unsigned pre = (unsigned)__popcll(msk & ltmask);
                unsigned fb  = (__float_as_uint(av[j]) + 0x8000u) & 0xFFFF0000u;
                rl[cur + pre] = fb | (unsigned)(pos * 256 + lane * 4 + j);
              }
              cur += cnt;
            } else {
              ovf = true;  // statistically unreachable at ~1%
            }
          }
        }
        if (lane == 0) counts[e & 1][w] = ovf ? 0xFFFFFFFFu : cur;
      }
    } else {
      // ---------------- GATHER role: row from epoch e-1
      if (e >= 1) {
        const int gw = w - 4;
        const int m  = row0 + (e - 1) * 4 + gw;
        const unsigned n = counts[(e - 1) & 1][gw];
        const unsigned* rl = &lists[(e - 1) & 1][gw][0];
        float a0 = 0.f, a1 = 0.f, a2 = 0.f, a3 = 0.f,
              a4 = 0.f, a5 = 0.f, a6 = 0.f, a7 = 0.f;

        if (n == 0xFFFFFFFFu) {
          // exact fallback: fused re-scan (never taken at ~1% density)
          const float* arow = A + (size_t)m * KDIM;
          for (int it = 0; it < KDIM / 256; ++it) {
            f32x4 av = *(const f32x4*)(arow + it * 256 + lane * 4);
            #pragma unroll
            for (int j = 0; j < 4; ++j) {
              unsigned long long msk = __ballot(av[j] != 0.0f);
              while (msk) {
                int s = __builtin_ctzll(msk); msk &= msk - 1;
                float f = __shfl(av[j], s, 64);
                int v = it * 256 + s * 4 + j;
                u32x4 q = *(const u32x4*)(wtb + (size_t)v * (NDIM * 2) + lane * 16);
                FMA8(f, q);
              }
            }
          }
        } else if (n > 0) {
          // 4-deep static gather pipeline from the LDS list
          const int ni = (int)n;
          auto rdp = [&](int i) -> unsigned { return (i < ni) ? rl[i] : 0u; };
          unsigned p0 = rdp(0), p1 = rdp(1), p2 = rdp(2), p3 = rdp(3);
          const int ng = (ni + 3) >> 2;
          for (int t = 0; t < ng; ++t) {
            const float f0 = __uint_as_float(p0 & 0xFFFF0000u);
            const float f1 = __uint_as_float(p1 & 0xFFFF0000u);
            const float f2 = __uint_as_float(p2 & 0xFFFF0000u);
            const float f3 = __uint_as_float(p3 & 0xFFFF0000u);
            // padded slots: p=0 -> f=0, v=0 gathers row 0, adds 0
            u32x4 q0 = *(const u32x4*)(wtb + (size_t)(p0 & 8191u) * (NDIM * 2) + lane * 16);
            u32x4 q1 = *(const u32x4*)(wtb + (size_t)(p1 & 8191u) * (NDIM * 2) + lane * 16);
            u32x4 q2 = *(const u32x4*)(wtb + (size_t)(p2 & 8191u) * (NDIM * 2) + lane * 16);
            u32x4 q3 = *(const u32x4*)(wtb + (size_t)(p3 & 8191u) * (NDIM * 2) + lane * 16);
            if (t + 1 < ng) {
              int b = (t + 1) * 4;
              p0 = rdp(b); p1 = rdp(b + 1); p2 = rdp(b + 2); p3 = rdp(b + 3);
            }
            FMA8(f0, q0);
            FMA8(f1, q1);
            FMA8(f2, q2);
            FMA8(f3, q3);
          }
        }

        float* crow = C + (size_t)m * NDIM + lane * 8;
        f32x4 o0 = {tanhf(a0), tanhf(a1), tanhf(a2), tanhf(a3)};
        f32x4 o1 = {tanhf(a4), tanhf(a5), tanhf(a6), tanhf(a7)};
        __builtin_nontemporal_store(o0, (f32x4*)(crow + 0));
        __builtin_nontemporal_store(o1, (f32x4*)(crow + 4));
      }
    }
    __syncthreads();
  }
#undef FMA8
}

// ---------------------------------------------------------------------------
extern "C" void kernel_launch(void* const* d_in, const int* in_sizes, int n_in,
                              void* d_out, int out_size, void* d_ws, size_t ws_size,
                              hipStream_t stream) {
  const float* x = (const float*)d_in[0];  // [8192, 8192] f32
  const float* W = (const float*)d_in[1];  // [512, 8192]  f32
  float* out = (float*)d_out;              // [8192, 512]  f32
  __bf16* WT = (__bf16*)d_ws;              // [8192, 512]  bf16

  transpose_w<<<dim3(1024),         dim3(256), 0, stream>>>(W, WT);
  spmm_pipe  <<<dim3(M_ROWS / RPB), dim3(512), 0, stream>>>(x, WT, out);
}